// Round 1
// baseline (192.732 us; speedup 1.0000x reference)
//
#include <hip/hip_runtime.h>

#define NV 4096
#define NN 7
#define KK1 49     // 7*7
#define KK2 169    // 13*13
#define C0 16
#define C1 32
#define C2 32
#define F1LEN 1568   // C1*KK1
#define F1PAD 56     // 49 -> 56 padded row
#define AGPAD 177    // 169 -> 177 padded row

// ---------------- Level 1: labels -> f1 (flat [NV][1568] f32, natural y-flat order)
__global__ __launch_bounds__(64) void lvl1_kernel(
    const float* __restrict__ labels, const int* __restrict__ nbrs,
    const float* __restrict__ mask1, const float* __restrict__ adj1,
    const float* __restrict__ W1, const float* __restrict__ b1,
    const float* __restrict__ al1, float* __restrict__ f1out)
{
    __shared__ float Ls[NN][C0];
    __shared__ float m1s[NN][7];
    __shared__ float a1s[KK1];
    __shared__ float aggs[C0 * KK1];   // 784, flat index c*49+ij
    __shared__ float W1s[C1 * 17];     // pad 16->17 (17 coprime 32: conflict-free)
    __shared__ float b1s[C1];
    int v = blockIdx.x, t = threadIdx.x;

    for (int e = t; e < NN * C0; e += 64) {
        int u = e >> 4, c = e & 15;
        Ls[u][c] = labels[(size_t)nbrs[v * NN + u] * C0 + c];
    }
    for (int e = t; e < KK1; e += 64) {
        m1s[e / 7][e % 7] = mask1[(size_t)v * KK1 + e];
        a1s[e] = adj1[(size_t)v * KK1 + e];
    }
    for (int e = t; e < C1 * C0; e += 64)
        W1s[(e >> 4) * 17 + (e & 15)] = W1[e];
    if (t < C1) b1s[t] = b1[t];
    float alpha = al1[0];
    __syncthreads();

    // agg[c][i][j] = sum_u L[u][c]*m1[u][i]*m1[u][j] + alpha*adj1[i][j]
    for (int e = t; e < C0 * KK1; e += 64) {
        int c = e / KK1, ij = e % KK1, i = ij / 7, j = ij % 7;
        float s = 0.f;
        #pragma unroll
        for (int u = 0; u < NN; ++u)
            s += Ls[u][c] * (m1s[u][i] * m1s[u][j]);
        aggs[e] = s + alpha * a1s[ij];
    }
    __syncthreads();

    // y[p][co] = relu(b1[co] + sum_c agg_flat[p*16+c] * W1[co][c]); store at flat e=p*32+co
    int co = t & 31;
    for (int e = t; e < F1LEN; e += 64) {
        int p = e >> 5;
        float s = b1s[co];
        #pragma unroll
        for (int c = 0; c < C0; ++c)
            s += aggs[p * C0 + c] * W1s[co * 17 + c];
        f1out[(size_t)v * F1LEN + e] = fmaxf(s, 0.f);
    }
}

// ---------------- Level 2 + g_repr accumulation
__global__ __launch_bounds__(192) void lvl2_kernel(
    const float* __restrict__ f1, const int* __restrict__ nbrs,
    const int* __restrict__ idx2, const float* __restrict__ mask2,
    const float* __restrict__ adj2, const float* __restrict__ W2,
    const float* __restrict__ b2, const float* __restrict__ al2,
    float* __restrict__ gr)
{
    __shared__ float f1s[C1 * F1PAD];   // neighbor f1 row, [c][ij] pad 56
    __shared__ float aggT[C1 * AGPAD];  // transposed agg rows: [c2][p] pad 177
    __shared__ float W2s[C2 * C1];      // row-major; read as uniform-address float4
    __shared__ float b2s[C2];
    __shared__ float grs[C2];
    __shared__ int   nbs[NN];
    int v = blockIdx.x, t = threadIdx.x;

    if (t < NN) nbs[t] = nbrs[v * NN + t];
    if (t < C2) { b2s[t] = b2[t]; grs[t] = 0.f; }
    for (int e = t; e < C2 * C1; e += 192) W2s[e] = W2[e];
    float alpha = al2[0];

    bool act = (t < KK2);
    float mmr[NN]; int qr[NN];
    float acc[C1];
    if (act) {
        int i = t / 13, j = t % 13;
        const float* mbase = mask2 + (size_t)v * NN * 13;
        const int*   ibase = idx2 + (size_t)v * NN * 13;
        #pragma unroll
        for (int u = 0; u < NN; ++u) {
            mmr[u] = mbase[u * 13 + i] * mbase[u * 13 + j];
            qr[u]  = ibase[u * 13 + i] * 7 + ibase[u * 13 + j];
        }
    }
    #pragma unroll
    for (int c = 0; c < C1; ++c) acc[c] = 0.f;

    // precompute staging LDS destinations
    int dst[9]; int nd = 0;
    for (int e = t; e < F1LEN; e += 192) dst[nd++] = (e / 49) * F1PAD + (e % 49);

    for (int u = 0; u < NN; ++u) {
        __syncthreads();   // covers init LDS + previous-iter readers of f1s
        const float* src = f1 + (size_t)nbs[u] * F1LEN;
        {
            int k = 0;
            for (int e = t; e < F1LEN; e += 192) f1s[dst[k++]] = src[e];
        }
        __syncthreads();
        if (act) {
            float mv = mmr[u]; int q = qr[u];
            #pragma unroll
            for (int c = 0; c < C1; ++c)
                acc[c] += mv * f1s[c * F1PAD + q];
        }
    }

    // + al2*adj2[ij] (same for all c) ; write transposed agg rows
    if (act) {
        float a2v = alpha * adj2[(size_t)v * KK2 + t];
        #pragma unroll
        for (int c = 0; c < C1; ++c) {
            int f = c * KK2 + t;            // flat index of agg2
            aggT[(f & 31) * AGPAD + (f >> 5)] = acc[c] + a2v;
        }
    }
    __syncthreads();

    // matmul row p = t: y[p][co] = relu(b2[co] + sum_c2 aggflat[p*32+c2]*W2[co][c2])
    // fold into g_repr channel (p*32+co)/169 : at most 2 channels per thread
    if (act) {
        int p = t;
        float ar[C1];
        #pragma unroll
        for (int c2 = 0; c2 < C1; ++c2) ar[c2] = aggT[c2 * AGPAD + p];
        int chA = (p * 32) / KK2;
        int csplit = KK2 - (p * 32 - chA * KK2);   // co < csplit -> chA, else chA+1
        float sA = 0.f, sB = 0.f;
        #pragma unroll
        for (int co = 0; co < C2; ++co) {
            float s = b2s[co];
            #pragma unroll
            for (int k = 0; k < 8; ++k) {
                float4 w = *(const float4*)(&W2s[co * C1 + 4 * k]);
                s += ar[4*k+0]*w.x + ar[4*k+1]*w.y + ar[4*k+2]*w.z + ar[4*k+3]*w.w;
            }
            s = fmaxf(s, 0.f);
            if (co < csplit) sA += s; else sB += s;
        }
        atomicAdd(&grs[chA], sA);
        if (csplit < 32) atomicAdd(&grs[chA + 1], sB);
    }
    __syncthreads();
    if (t < C2) atomicAdd(&gr[t], grs[t]);
}

// ---------------- final FC + output layout [output(1), g_repr(32)]
__global__ __launch_bounds__(64) void fc_kernel(
    const float* __restrict__ gr, const float* __restrict__ Wfc,
    const float* __restrict__ bfc, float* __restrict__ out)
{
    int t = threadIdx.x;
    float g = (t < C2) ? gr[t] : 0.f;
    if (t < C2) out[1 + t] = g;
    float p = (t < C2) ? g * Wfc[t] : 0.f;
    #pragma unroll
    for (int off = 32; off > 0; off >>= 1) p += __shfl_down(p, off);
    if (t == 0) out[0] = p + bfc[0];
}

extern "C" void kernel_launch(void* const* d_in, const int* in_sizes, int n_in,
                              void* d_out, int out_size, void* d_ws, size_t ws_size,
                              hipStream_t stream)
{
    const float* labels = (const float*)d_in[0];
    const int*   nbrs   = (const int*)d_in[1];
    /* d_in[2] = idx1 : provably all zeros (prev rfield has size 1) -> unused */
    const float* mask1  = (const float*)d_in[3];
    const int*   idx2   = (const int*)d_in[4];
    const float* mask2  = (const float*)d_in[5];
    const float* adj1   = (const float*)d_in[6];
    const float* adj2   = (const float*)d_in[7];
    const float* W1     = (const float*)d_in[8];
    const float* b1     = (const float*)d_in[9];
    const float* W2     = (const float*)d_in[10];
    const float* b2     = (const float*)d_in[11];
    const float* al1    = (const float*)d_in[12];
    const float* al2    = (const float*)d_in[13];
    const float* Wfc    = (const float*)d_in[14];
    const float* bfc    = (const float*)d_in[15];

    float* f1 = (float*)d_ws;
    float* gr = (float*)((char*)d_ws + (size_t)NV * F1LEN * sizeof(float));

    hipMemsetAsync(gr, 0, C2 * sizeof(float), stream);
    lvl1_kernel<<<NV, 64, 0, stream>>>(labels, nbrs, mask1, adj1, W1, b1, al1, f1);
    lvl2_kernel<<<NV, 192, 0, stream>>>(f1, nbrs, idx2, mask2, adj2, W2, b2, al2, gr);
    fc_kernel<<<1, 64, 0, stream>>>(gr, Wfc, bfc, (float*)d_out);
}